// Round 1
// 153.426 us; speedup vs baseline: 1.3959x; 1.3959x over previous
//
#include <hip/hip_runtime.h>
#include <math.h>

// VQ-VAE quantize: z [32,8,16,16] f32, codebook [16384,8] f32
// N=8192 rows, K=16384 codes, D=8.
// Outputs (concatenated f32): z_q [65536], loss [1], idx-as-float [8192].
//
// f[n,k] = 200*dot(z_n,e_k) - 100*||e_k||^2  (= -d/T + row const; softmax &
// argmax shift-invariant). exp underflows for f - m < -87 (matches fp32 ref).
//
// R3: pass1 was latency-bound (VALUBusy 23.7%). Now: 4 rows/wave (2x arith
// intensity per codebook byte, halves L1/L2 traffic) + explicit double-
// buffered register prefetch (batch=4 k-iters, ping-pong A/B, static
// indexing only) so codebook loads for batch i+1 are in flight during
// compute of batch i. Threshold tightening every 32 iters (was 16) --
// tightening is load-bearing: it keeps candidate counts << CAP so the
// serial fixup path stays dead. prep_cb also zeroes ws (memset fused out).

#define KCODES 16384
#define CAP 192

__device__ __forceinline__ float dot8s(const float (&z)[8], float4 c0,
                                       float4 c1, float b) {
    float a = fmaf(z[0], c0.x, b);
    a = fmaf(z[1], c0.y, a);
    a = fmaf(z[2], c0.z, a);
    a = fmaf(z[3], c0.w, a);
    a = fmaf(z[4], c1.x, a);
    a = fmaf(z[5], c1.y, a);
    a = fmaf(z[6], c1.z, a);
    a = fmaf(z[7], c1.w, a);
    return a;
}

// ---------------- prep: codebook norms + workspace zeroing ----------------
__global__ __launch_bounds__(256) void prep_cb(const float* __restrict__ cb,
                                               float* __restrict__ bk,
                                               float* __restrict__ avgp,
                                               int* __restrict__ flag,
                                               float* __restrict__ scal) {
    int k = blockIdx.x * 256 + threadIdx.x;
    const float4* c4 = (const float4*)cb;
    float4 c0 = c4[2 * k], c1 = c4[2 * k + 1];
    float nrm = c0.x * c0.x + c0.y * c0.y + c0.z * c0.z + c0.w * c0.w
              + c1.x * c1.x + c1.y * c1.y + c1.z * c1.z + c1.w * c1.w;
    bk[k] = -100.0f * nrm;
    avgp[k] = 0.0f;              // ws is poisoned each launch: zero it here
    if (k < 8192) flag[k] = 0;
    if (k < 8)    scal[k] = 0.0f;
}

// ---------------- pass 1: single sweep, candidate recording ----------------
// wave = 4 rows, lane strides K by 64. Grid 512 blocks (16 rows/block).
__global__ __launch_bounds__(256, 2) void pass1(
    const float* __restrict__ z, const float* __restrict__ cb,
    const float* __restrict__ bk, float* __restrict__ mrow,
    int* __restrict__ flag, float* __restrict__ out_zq,
    float* __restrict__ out_idx, float* __restrict__ scal,
    float* __restrict__ avgp)
{
    __shared__ float wfb[16][CAP];
    __shared__ int   wkb[16][CAP];
    __shared__ int   cnt[16];
    __shared__ float redSq[4], redEnt[4];

    const int wave = threadIdx.x >> 6;
    const int lane = threadIdx.x & 63;
    const int w4 = wave * 4;
    const int row0 = blockIdx.x * 16 + w4;

    // load 4 rows (broadcast) and fold the 200x scale in
    float zr[4][8];
#pragma unroll
    for (int r = 0; r < 4; ++r) {
        int row = row0 + r;
        const float* p = z + (row >> 8) * 2048 + (row & 255);
#pragma unroll
        for (int c = 0; c < 8; ++c) zr[r][c] = 200.0f * p[c * 256];
    }
    if (lane < 4) cnt[w4 + lane] = 0;
    __syncthreads();

    const float4* c4 = (const float4*)cb;
    float m[4], mt[4];
#pragma unroll
    for (int r = 0; r < 4; ++r) m[r] = -3.4e38f;

    // warm-up: 512 codes, max only (no recording), then share across lanes
#pragma unroll
    for (int j = 0; j < 8; ++j) {
        int k = lane + 64 * j;
        float4 c0 = c4[2 * k], c1 = c4[2 * k + 1];
        float b = bk[k];
#pragma unroll
        for (int r = 0; r < 4; ++r) m[r] = fmaxf(m[r], dot8s(zr[r], c0, c1, b));
    }
#pragma unroll
    for (int off = 32; off; off >>= 1) {
#pragma unroll
        for (int r = 0; r < 4; ++r) m[r] = fmaxf(m[r], __shfl_xor(m[r], off));
    }
#pragma unroll
    for (int r = 0; r < 4; ++r) mt[r] = m[r] - 87.0f;

    // ---- main sweep: 64 batches x 4 k-iters, double-buffered prefetch ----
    float4 A0[4], A1[4]; float Ab[4];
    float4 B0[4], B1[4]; float Bb[4];

    auto loadA = [&](int bat) {
#pragma unroll
        for (int jj = 0; jj < 4; ++jj) {
            int k = lane + bat * 256 + 64 * jj;
            A0[jj] = c4[2 * k]; A1[jj] = c4[2 * k + 1]; Ab[jj] = bk[k];
        }
    };
    auto loadB = [&](int bat) {
#pragma unroll
        for (int jj = 0; jj < 4; ++jj) {
            int k = lane + bat * 256 + 64 * jj;
            B0[jj] = c4[2 * k]; B1[jj] = c4[2 * k + 1]; Bb[jj] = bk[k];
        }
    };
    // fast path per k: 32 FMA + 4 cmp; rare work behind wave-uniform __any
    auto comp = [&](int bat, const float4 (&P0)[4], const float4 (&P1)[4],
                    const float (&PB)[4]) {
#pragma unroll
        for (int jj = 0; jj < 4; ++jj) {
            float f0 = dot8s(zr[0], P0[jj], P1[jj], PB[jj]);
            float f1 = dot8s(zr[1], P0[jj], P1[jj], PB[jj]);
            float f2 = dot8s(zr[2], P0[jj], P1[jj], PB[jj]);
            float f3 = dot8s(zr[3], P0[jj], P1[jj], PB[jj]);
            bool h0 = f0 > mt[0], h1 = f1 > mt[1];
            bool h2 = f2 > mt[2], h3 = f3 > mt[3];
            if (__any(h0 | h1 | h2 | h3)) {      // wave-uniform, rare
                int k = lane + bat * 256 + 64 * jj;
                if (h0) { m[0] = fmaxf(m[0], f0); mt[0] = m[0] - 87.0f;
                    int s_ = atomicAdd(&cnt[w4 + 0], 1);
                    if (s_ < CAP) { wfb[w4 + 0][s_] = f0; wkb[w4 + 0][s_] = k; } }
                if (h1) { m[1] = fmaxf(m[1], f1); mt[1] = m[1] - 87.0f;
                    int s_ = atomicAdd(&cnt[w4 + 1], 1);
                    if (s_ < CAP) { wfb[w4 + 1][s_] = f1; wkb[w4 + 1][s_] = k; } }
                if (h2) { m[2] = fmaxf(m[2], f2); mt[2] = m[2] - 87.0f;
                    int s_ = atomicAdd(&cnt[w4 + 2], 1);
                    if (s_ < CAP) { wfb[w4 + 2][s_] = f2; wkb[w4 + 2][s_] = k; } }
                if (h3) { m[3] = fmaxf(m[3], f3); mt[3] = m[3] - 87.0f;
                    int s_ = atomicAdd(&cnt[w4 + 3], 1);
                    if (s_ < CAP) { wfb[w4 + 3][s_] = f3; wkb[w4 + 3][s_] = k; } }
            }
        }
    };

    loadA(0);                                    // prime the pipeline
    for (int t = 0; t < 8; ++t) {                // 8 super-blocks of 2048 codes
#pragma unroll
        for (int s = 0; s < 4; ++s) {
            const int b0 = t * 8 + s * 2;
            loadB((b0 + 1) & 63);                // prefetch next batch
            comp(b0, A0, A1, Ab);
            loadA((b0 + 2) & 63);                // (&63: final load wraps, unused)
            comp(b0 + 1, B0, B1, Bb);
        }
        // tighten every lane's threshold to the wave-global running max
#pragma unroll
        for (int off = 32; off; off >>= 1) {
#pragma unroll
            for (int r = 0; r < 4; ++r)
                m[r] = fmaxf(m[r], __shfl_xor(m[r], off));
        }
#pragma unroll
        for (int r = 0; r < 4; ++r) mt[r] = m[r] - 87.0f;
    }
    __syncthreads();   // drain this wave's LDS atomics/writes before reads

    // flush: per row, compute s, t, argmin, entropy, avg_probs from candidates
    float entAcc = 0.0f, sqAcc = 0.0f;
#pragma unroll
    for (int r = 0; r < 4; ++r) {
        const int br = w4 + r;
        const int row = row0 + r;
        const float mm = m[r];
        int c = cnt[br];
        if (c > CAP) {                       // overflow: defer to fixup
            if (lane == 0) { flag[row] = 1; mrow[row] = mm; }
            continue;
        }
        float sl = 0.0f, tl = 0.0f;
        int kmin = 0x7fffffff;
        for (int i = lane; i < c; i += 64) {
            float x = wfb[br][i] - mm;       // <= 0; == 0 at the argmax
            float e = 0.0f;
            if (x > -87.0f) {
                e = __expf(x);
                sl += e;
                tl = fmaf(x, e, tl);
                if (x == 0.0f) kmin = min(kmin, wkb[br][i]);
            }
            wfb[br][i] = e;                  // stash e for the flush loop
        }
#pragma unroll
        for (int off = 32; off; off >>= 1) {
            sl += __shfl_xor(sl, off);
            tl += __shfl_xor(tl, off);
            kmin = min(kmin, __shfl_xor(kmin, off));
        }
        float rs = 1.0f / sl;
        for (int i = lane; i < c; i += 64) {
            float e = wfb[br][i];
            if (e != 0.0f) atomicAdd(&avgp[wkb[br][i]], e * rs);
        }
        if (lane == 0) {
            entAcc += tl * rs - logf(sl);
            out_idx[row] = (float)kmin;
            float4 q0 = c4[2 * kmin], q1 = c4[2 * kmin + 1];
            float qv[8] = {q0.x, q0.y, q0.z, q0.w, q1.x, q1.y, q1.z, q1.w};
            int bb = row >> 8, hw = row & 255;
            const float* zraw = z + bb * 2048 + hw;   // raw row (L1-hot)
            float* o = out_zq + bb * 2048 + hw;
#pragma unroll
            for (int ch = 0; ch < 8; ++ch) {
                float raw = zraw[ch * 256];
                o[ch * 256] = qv[ch];
                float dq = qv[ch] - raw;
                sqAcc += dq * dq;
            }
        }
    }
    if (lane == 0) { redSq[wave] = sqAcc; redEnt[wave] = entAcc; }
    __syncthreads();
    if (threadIdx.x == 0) {
        atomicAdd(&scal[0], redSq[0] + redSq[1] + redSq[2] + redSq[3]);
        atomicAdd(&scal[1], redEnt[0] + redEnt[1] + redEnt[2] + redEnt[3]);
    }
}

// ---------------- fixup: full serial recompute for overflowed rows ----------
// Dead code in practice (CAP=192 >> typical ~20 candidates); correctness net.
__global__ __launch_bounds__(256) void fixup(
    const float* __restrict__ z, const float* __restrict__ cb,
    const float* __restrict__ bk, const float* __restrict__ mrow,
    const int* __restrict__ flag, float* __restrict__ avgp,
    float* __restrict__ out_zq, float* __restrict__ out_idx,
    float* __restrict__ scal)
{
    int n = blockIdx.x * 256 + threadIdx.x;
    if (n >= 8192 || flag[n] == 0) return;
    float zraw[8], zs[8];
    int bb = n >> 8, hw = n & 255;
#pragma unroll
    for (int c = 0; c < 8; ++c) {
        zraw[c] = z[bb * 2048 + c * 256 + hw];
        zs[c] = 200.0f * zraw[c];
    }
    const float4* c4 = (const float4*)cb;
    float m = mrow[n];
    float s = 0.0f, t = 0.0f;
    int kmin = 0x7fffffff;
    for (int k = 0; k < KCODES; ++k) {
        float f = dot8s(zs, c4[2 * k], c4[2 * k + 1], bk[k]);
        float x = f - m;
        if (x > -87.0f) {
            float e = __expf(x);
            s += e; t = fmaf(x, e, t);
            if (x == 0.0f) kmin = min(kmin, k);
        }
    }
    float rs = 1.0f / s;
    for (int k = 0; k < KCODES; ++k) {
        float f = dot8s(zs, c4[2 * k], c4[2 * k + 1], bk[k]);
        float x = f - m;
        if (x > -87.0f) atomicAdd(&avgp[k], __expf(x) * rs);
    }
    out_idx[n] = (float)kmin;
    float sq = 0.0f;
#pragma unroll
    for (int c = 0; c < 8; ++c) {
        float q = cb[kmin * 8 + c];
        out_zq[bb * 2048 + c * 256 + hw] = q;
        float dq = q - zraw[c];
        sq += dq * dq;
    }
    atomicAdd(&scal[0], sq);
    atomicAdd(&scal[1], t * rs - logf(s));
}

// ---------------- finalize: avg entropy + loss assembly ----------------
__global__ __launch_bounds__(256) void finalize(
    const float* __restrict__ avgp, const float* __restrict__ scal,
    float* __restrict__ out_loss)
{
    float acc = 0.0f;
    for (int k = threadIdx.x; k < KCODES; k += 256) {
        float avg = avgp[k] * (1.0f / 8192.0f);
        acc += avg * logf(avg + 1e-5f);    // avg==0 contributes exactly 0
    }
#pragma unroll
    for (int off = 32; off > 0; off >>= 1) acc += __shfl_xor(acc, off);
    __shared__ float red[4];
    int wave = threadIdx.x >> 6, lane = threadIdx.x & 63;
    if (lane == 0) red[wave] = acc;
    __syncthreads();
    if (threadIdx.x == 0) {
        float T = red[0] + red[1] + red[2] + red[3];   // sum avg*log(avg+eps)
        // loss = 1.25*mean((zq-z)^2) + 0.1*(sample_entropy - avg_entropy)
        float loss = 1.25f * (scal[0] * (1.0f / 65536.0f))
                   + 0.1f * (T - scal[1] * (1.0f / 8192.0f));
        out_loss[0] = loss;
    }
}

extern "C" void kernel_launch(void* const* d_in, const int* in_sizes, int n_in,
                              void* d_out, int out_size, void* d_ws, size_t ws_size,
                              hipStream_t stream) {
    const float* z  = (const float*)d_in[0];   // [32,8,16,16]
    const float* cb = (const float*)d_in[1];   // [16384,8]
    float* out = (float*)d_out;
    float* ws  = (float*)d_ws;

    // workspace layout (floats)
    float* bk   = ws;                // 16384 : -100*||e_k||^2
    float* avgp = ws + 16384;        // 16384 : sum_n p[n,k]
    float* scal = ws + 32768;        // 2     : [sq, entS]  (+6 pad)
    int*   flag = (int*)(ws + 32776);// 8192  : overflow flags
    float* mrow = ws + 40968;        // 8192  : m for flagged rows

    float* out_zq   = out;           // 65536
    float* out_loss = out + 65536;   // 1
    float* out_idx  = out + 65537;   // 8192

    // prep_cb zeroes avgp/scal/flag (ws is re-poisoned every launch)
    prep_cb <<<64,  256, 0, stream>>>(cb, bk, avgp, flag, scal);
    pass1   <<<512, 256, 0, stream>>>(z, cb, bk, mrow, flag, out_zq, out_idx,
                                      scal, avgp);
    fixup   <<<32,  256, 0, stream>>>(z, cb, bk, mrow, flag, avgp, out_zq,
                                      out_idx, scal);
    finalize<<<1,   256, 0, stream>>>(avgp, scal, out_loss);
}